// Round 7
// baseline (316.710 us; speedup 1.0000x reference)
//
#include <hip/hip_runtime.h>

typedef _Float16 v8h __attribute__((ext_vector_type(8)));
typedef float    v4f __attribute__((ext_vector_type(4)));

#define MFMA16(A,B,C) __builtin_amdgcn_mfma_f32_16x16x32_f16((A),(B),(C),0,0,0)

#define RPB 16
#define TT  256
#define HH  64
#define KST 136      // f16 stride per A row: k 0-63 = ha, 64-127 = hb, 8 pad
// Interp-LUT index space: F = 2048*z + 32768, entry = F>>8 (256 entries,
// z in [-16,16), h = 0.125), frac = F & 255. sigma gates scale 2048;
// g gate scale 4096 (tanh(z) = 2*sigma(2z)-1, arg range +-8 as before).
#define FSC  2048.0f
#define FSG  4096.0f
#define FOFF 32768.0f
#define FCLMP 65535.0f
#define TSC2 -2.88539008f // -2*log2(e): tanh(c)=2*rcp(1+exp2(c*TSC2))-1

// R7: kill the sigma-gather bank conflicts (632 of ~1730 LDS cyc/CU-step;
// LDS pipe ~70% busy was the R6 leader). The 8192-entry NN LUT's random
// indices collide ~4-way; replaced by a 256-entry table REPLICATED across
// all 32 banks (lut[entry][bank], float2 {sigma, slope/256}): lane l always
// hits banks 2(l&31) -> every bank exactly 4 accesses/wave-gather = pure
// bandwidth, zero conflicts. Coarse table needs linear interp (+4 VALU +
// 1 fma per value); f32 entries keep error <= old NN (interp ~1e-4).
// Keeps R6: 16 real rows, layer-split waves (w<4 L0: 8 MFMAs, w>=4 L1: 16),
// no MFMA dup, 1 barrier/step, exp2 tanh(c).
__global__ __launch_bounds__(512, 2)
void lstm2_kernel(const float* __restrict__ x,     // [4096][256]
                  const float* __restrict__ Wih0,  // [256][1]
                  const float* __restrict__ Whh0,  // [256][64]
                  const float* __restrict__ bih0,
                  const float* __restrict__ bhh0,
                  const float* __restrict__ Wih1,  // [256][64]
                  const float* __restrict__ Whh1,  // [256][64]
                  const float* __restrict__ bih1,
                  const float* __restrict__ bhh1,
                  const float* __restrict__ Wlin,  // [64][64]
                  const float* __restrict__ blin,
                  float* __restrict__ out)         // [4096][64]
{
    __shared__ float xl[TT][RPB];                      // 16 KB
    __shared__ __align__(16) _Float16 hs[2][RPB][KST]; // 8.5 KB
    __shared__ float hbF[RPB][HH];                     // 4 KB
    __shared__ float2 lut[256 * 32];                   // 64 KB replicated table

    const int tid  = threadIdx.x;
    const int w    = tid >> 6;         // wave 0..7
    const int l15  = tid & 15;         // A-frag row = batch row (no dup)
    const int q    = (tid & 63) >> 4;  // k-group / pointwise row-quad
    const int row0 = (int)blockIdx.x * RPB;
    const int jj   = (w & 3) * 16 + l15;  // gate column 0..63
    const bool isA = (w < 4);          // wave-uniform: layer0 vs layer1
    const int  mr  = q * 4;            // my pointwise row base (0,4,8,12)
    const int  loff = (tid & 31) * 8;  // my bank replica (byte offset)

    for (int idx = tid; idx < RPB * TT; idx += 512) {
        int m = idx & 15, t = idx >> 4;
        xl[t][m] = x[(row0 + m) * TT + t];
    }
    for (int idx = tid; idx < 2 * RPB * KST; idx += 512)
        ((_Float16*)hs)[idx] = (_Float16)0.f;
    for (int i = tid; i < 256 * 32; i += 512) {
        int e = i >> 5;
        float z  = (e - 128) * 0.125f;
        float s0 = 1.0f / (1.0f + __expf(-z));
        float s1 = 1.0f / (1.0f + __expf(-(z + 0.125f)));
        lut[i] = (float2){s0, (s1 - s0) * (1.0f / 256.0f)};
    }

    // sigma via conflict-free replicated table + linear interp.
    // F is the prescaled MFMA acc (= 2048*z + 32768).
    auto lutv = [&](float F) -> float {
        F = __builtin_amdgcn_fmed3f(F, 0.0f, FCLMP);
        int ia = ((int)F) & 0xFF00;            // entry*256 (byte offset)
        float fr = F - (float)ia;              // [0,256)
        float2 s = *(const float2*)((const char*)lut + ia + loff);
        return fmaf(s.y, fr, s.x);
    };
    // tanh via hardware exp2+rcp (near-exact, no gather)
    auto tanhf_fast = [&](float c) -> float {
        return fmaf(2.f, __builtin_amdgcn_rcpf(1.f + __builtin_exp2f(c * TSC2)), -1.f);
    };

    // ---- register-stationary weights (only MY layer's), F index space ----
    float wi0s[4], b0s[4];
    v8h   wh0[4][2];
    v4f   b1v[4];
    v8h   wi1[4][2], wh1[4][2];
    if (isA) {
        #pragma unroll
        for (int tau = 0; tau < 4; tau++) {
            float sc = (tau == 2) ? FSG : FSC;
            int n = tau * 64 + jj;
            wi0s[tau] = Wih0[n] * sc;
            b0s[tau]  = (bih0[n] + bhh0[n]) * sc + FOFF;
            #pragma unroll
            for (int kk = 0; kk < 2; kk++) {
                int k0 = kk * 32 + q * 8;   // B-frag: B[k0..k0+7][n=lane&15]
                v8h a;
                #pragma unroll
                for (int j = 0; j < 8; j++)
                    a[j] = (_Float16)(Whh0[n * HH + k0 + j] * sc);
                wh0[tau][kk] = a;
            }
        }
    } else {
        #pragma unroll
        for (int tau = 0; tau < 4; tau++) {
            float sc = (tau == 2) ? FSG : FSC;
            int n = tau * 64 + jj;
            float b1 = (bih1[n] + bhh1[n]) * sc + FOFF;
            b1v[tau] = (v4f){b1, b1, b1, b1};
            #pragma unroll
            for (int kk = 0; kk < 2; kk++) {
                int k0 = kk * 32 + q * 8;
                v8h b, c;
                #pragma unroll
                for (int j = 0; j < 8; j++) {
                    b[j] = (_Float16)(Wih1[n * HH + k0 + j] * sc);
                    c[j] = (_Float16)(Whh1[n * HH + k0 + j] * sc);
                }
                wi1[tau][kk] = b; wh1[tau][kk] = c;
            }
        }
    }

    float cs[4] = {0.f, 0.f, 0.f, 0.f};  // c-state of MY layer, rows mr..mr+3
    __syncthreads();

    // ---- prologue t=0: ha(0) from x(0) only (layer-0 waves) ----
    if (isA) {
        #pragma unroll
        for (int r = 0; r < 4; r++) {
            int m = mr + r;
            float xv = xl[0][m];
            float iv = lutv(fmaf(xv, wi0s[0], b0s[0]));
            float gv = fmaf(2.f, lutv(fmaf(xv, wi0s[2], b0s[2])), -1.f);
            float ov = lutv(fmaf(xv, wi0s[3], b0s[3]));
            cs[r] = iv * gv;
            hs[0][m][jj] = (_Float16)(ov * tanhf_fast(cs[r]));
        }
    }
    __syncthreads();

    // step k: reads buf[p] {ha(k-1), hb(k-2)}, writes buf[pw] {ha(k), hb(k-1)}
    auto step = [&](int k, int p, int pw, bool last) {
        if (isA) {
            // ---- layer 0: 8 MFMAs, x via rank-1 fmaf init ----
            v8h a0 = *(const v8h*)&hs[p][l15][q * 8];          // ha k 0-31
            v8h a1 = *(const v8h*)&hs[p][l15][32 + q * 8];     // ha k 32-63
            int kx = (k < TT) ? k : (TT - 1);                  // k=256: junk
            v4f xv = *(const v4f*)&xl[kx][mr];

            v4f acc[4];
            #pragma unroll
            for (int tau = 0; tau < 4; tau++) {
                #pragma unroll
                for (int r = 0; r < 4; r++)
                    acc[tau][r] = fmaf(xv[r], wi0s[tau], b0s[tau]);
            }
            #pragma unroll
            for (int tau = 0; tau < 4; tau++) {
                acc[tau] = MFMA16(a0, wh0[tau][0], acc[tau]);
                acc[tau] = MFMA16(a1, wh0[tau][1], acc[tau]);
            }
            // all 16 interp-gathers issued together (conflict-free banks)
            float sv0[4], sv1[4], sv2[4], sv3[4];
            #pragma unroll
            for (int r = 0; r < 4; r++) {
                sv0[r] = lutv(acc[0][r]);
                sv1[r] = lutv(acc[1][r]);
                sv2[r] = lutv(acc[2][r]);
                sv3[r] = lutv(acc[3][r]);
            }
            _Float16* wp = &hs[pw][mr][jj];
            #pragma unroll
            for (int r = 0; r < 4; r++) {
                float iv = sv0[r], fv = sv1[r];
                float gv = fmaf(2.f, sv2[r], -1.f);
                float ov = sv3[r];
                cs[r] = fmaf(fv, cs[r], iv * gv);
                wp[r * KST] = (_Float16)(ov * tanhf_fast(cs[r]));
            }
        } else {
            // ---- layer 1: 16 MFMAs over [ha | hb], bias as C operand ----
            v8h a0 = *(const v8h*)&hs[p][l15][q * 8];          // ha k 0-31
            v8h a1 = *(const v8h*)&hs[p][l15][32 + q * 8];     // ha k 32-63
            v8h b0 = *(const v8h*)&hs[p][l15][64 + q * 8];     // hb k 0-31
            v8h b1 = *(const v8h*)&hs[p][l15][96 + q * 8];     // hb k 32-63

            v4f acc[4];
            #pragma unroll
            for (int tau = 0; tau < 4; tau++)
                acc[tau] = MFMA16(a0, wi1[tau][0], b1v[tau]);
            #pragma unroll
            for (int tau = 0; tau < 4; tau++) {
                acc[tau] = MFMA16(a1, wi1[tau][1], acc[tau]);
                acc[tau] = MFMA16(b0, wh1[tau][0], acc[tau]);
                acc[tau] = MFMA16(b1, wh1[tau][1], acc[tau]);
            }
            float sv0[4], sv1[4], sv2[4], sv3[4];
            #pragma unroll
            for (int r = 0; r < 4; r++) {
                sv0[r] = lutv(acc[0][r]);
                sv1[r] = lutv(acc[1][r]);
                sv2[r] = lutv(acc[2][r]);
                sv3[r] = lutv(acc[3][r]);
            }
            _Float16* wp = &hs[pw][mr][64 + jj];
            #pragma unroll
            for (int r = 0; r < 4; r++) {
                float iv = sv0[r], fv = sv1[r];
                float gv = fmaf(2.f, sv2[r], -1.f);
                float ov = sv3[r];
                cs[r] = fmaf(fv, cs[r], iv * gv);
                float hv = ov * tanhf_fast(cs[r]);
                wp[r * KST] = (_Float16)hv;
                if (last) hbF[mr + r][jj] = hv;
            }
        }
        __syncthreads();
    };

    // k = 1..256 (k=256 = layer-1-only epilogue; its ha output junk-but-finite)
    for (int k = 1; k <= TT; k += 2) {
        step(k,     0, 1, false);
        step(k + 1, 1, 0, (k + 1) == TT);
    }

    // ---- out[m][n] = hbF[m][:] . Wlin[n][:] + blin[n] ----
    int m = tid >> 6;             // 0..15 (512 threads -> 8 waves map 16 rows? no:
    // 512 threads: tid>>6 = wave 0..7; need 16x64=1024 outputs from 512 lanes -> 2 each
    m = tid >> 5;                 // 0..15
    int n0 = (tid & 31) * 2;
    float a0o = blin[n0], a1o = blin[n0 + 1];
    #pragma unroll 8
    for (int j = 0; j < HH; j++) {
        float h = hbF[m][j];
        a0o = fmaf(h, Wlin[(n0 + 0) * HH + j], a0o);
        a1o = fmaf(h, Wlin[(n0 + 1) * HH + j], a1o);
    }
    out[(row0 + m) * HH + n0]     = a0o;
    out[(row0 + m) * HH + n0 + 1] = a1o;
}

extern "C" void kernel_launch(void* const* d_in, const int* in_sizes, int n_in,
                              void* d_out, int out_size, void* d_ws, size_t ws_size,
                              hipStream_t stream) {
    const float* x    = (const float*)d_in[0];
    const float* Wih0 = (const float*)d_in[1];
    const float* Whh0 = (const float*)d_in[2];
    const float* bih0 = (const float*)d_in[3];
    const float* bhh0 = (const float*)d_in[4];
    const float* Wih1 = (const float*)d_in[5];
    const float* Whh1 = (const float*)d_in[6];
    const float* bih1 = (const float*)d_in[7];
    const float* bhh1 = (const float*)d_in[8];
    const float* Wlin = (const float*)d_in[9];
    const float* blin = (const float*)d_in[10];
    // 4096 rows / 16 per block = 256 blocks = 1 block/CU, 8 waves (2/SIMD)
    lstm2_kernel<<<256, 512, 0, stream>>>(x, Wih0, Whh0, bih0, bhh0,
                                          Wih1, Whh1, bih1, bhh1,
                                          Wlin, blin, (float*)d_out);
}

// Round 8
// 312.520 us; speedup vs baseline: 1.0134x; 1.0134x over previous
//
#include <hip/hip_runtime.h>

typedef _Float16 v8h __attribute__((ext_vector_type(8)));
typedef float    v4f __attribute__((ext_vector_type(4)));

#define MFMA16(A,B,C) __builtin_amdgcn_mfma_f32_16x16x32_f16((A),(B),(C),0,0,0)

#define RPB 16
#define TT  256
#define HH  64
#define KST 136      // f16 stride per A row: k 0-63 = ha, 64-127 = hb, 8 pad
// i,f gates: interp table, ENTRY space F = 8z+128 (256 entries, z in [-16,16))
#define FSC_I 8.0f
#define FOFF_I 128.0f
#define FCL_I 255.999f
// g,o gates: NN-8192 LUT, index space F = 256z+4096.5 (g uses 512z: tanh trick)
#define SG_N 256.0f
#define TG_N 512.0f
#define IOFF_N 4096.5f
#define FCL_N 8191.0f
#define TSC2 -2.88539008f // -2*log2(e): tanh(c)=2*rcp(1+exp2(c*TSC2))-1

// R8: pipe-balanced sigma. R6 (all-NN: conflicts 632cy/CU-step, VALU 45%,
// 267us) and R7 (all-interp: conflicts ~96, VALU 66%, 281us) bracket a
// balance point: i,f via the 32-bank-replicated interp table (conflict-
// free; index math now fract-based: fmed3+fract+cvt+lshl_add, -2 VALU vs
// R7), g,o via the NN-8192 LUT (3 VALU, conflicty). NN gathers issued
// first so their serialization overlaps the interp VALU math. Keeps R6/R7:
// 16 real rows, layer-split waves (w<4 L0: 8 MFMAs, w>=4 L1: 16), no MFMA
// dup, 1 barrier/step, exp2 tanh(c) (2nd gather round stays dead).
__global__ __launch_bounds__(512, 2)
void lstm2_kernel(const float* __restrict__ x,     // [4096][256]
                  const float* __restrict__ Wih0,  // [256][1]
                  const float* __restrict__ Whh0,  // [256][64]
                  const float* __restrict__ bih0,
                  const float* __restrict__ bhh0,
                  const float* __restrict__ Wih1,  // [256][64]
                  const float* __restrict__ Whh1,  // [256][64]
                  const float* __restrict__ bih1,
                  const float* __restrict__ bhh1,
                  const float* __restrict__ Wlin,  // [64][64]
                  const float* __restrict__ blin,
                  float* __restrict__ out)         // [4096][64]
{
    __shared__ float xl[TT][RPB];                      // 16 KB
    __shared__ __align__(16) _Float16 hs[2][RPB][KST]; // 8.5 KB
    __shared__ float hbF[RPB][HH];                     // 4 KB
    __shared__ float2 lutI_t[256 * 32];                // 64 KB replicated interp
    __shared__ float  lutN_t[8192];                    // 32 KB NN sigma table

    const int tid  = threadIdx.x;
    const int w    = tid >> 6;         // wave 0..7
    const int l15  = tid & 15;         // A-frag row = batch row (no dup)
    const int q    = (tid & 63) >> 4;  // k-group / pointwise row-quad
    const int row0 = (int)blockIdx.x * RPB;
    const int jj   = (w & 3) * 16 + l15;  // gate column 0..63
    const bool isA = (w < 4);          // wave-uniform: layer0 vs layer1
    const int  mr  = q * 4;            // my pointwise row base (0,4,8,12)
    const int  loff = (tid & 31) * 8;  // interp-table bank replica (byte off)

    for (int idx = tid; idx < RPB * TT; idx += 512) {
        int m = idx & 15, t = idx >> 4;
        xl[t][m] = x[(row0 + m) * TT + t];
    }
    for (int idx = tid; idx < 2 * RPB * KST; idx += 512)
        ((_Float16*)hs)[idx] = (_Float16)0.f;
    for (int i = tid; i < 256 * 32; i += 512) {
        int e = i >> 5;
        float z  = (e - 128) * 0.125f;
        float s0 = 1.0f / (1.0f + __expf(-z));
        float s1 = 1.0f / (1.0f + __expf(-(z + 0.125f)));
        lutI_t[i] = (float2){s0, s1 - s0};   // slope per unit-frac
    }
    for (int i = tid; i < 8192; i += 512)
        lutN_t[i] = 1.0f / (1.0f + __expf(-(i - 4096) * (1.0f / 256.0f)));

    // conflict-free interp sigma; F = 8z+128 (entry space)
    auto lutI = [&](float F) -> float {
        F = __builtin_amdgcn_fmed3f(F, 0.0f, FCL_I);
        float fr = __builtin_amdgcn_fractf(F);
        int e = (int)F;
        float2 s = *(const float2*)((const char*)lutI_t + (e << 8) + loff);
        return fmaf(s.y, fr, s.x);
    };
    // NN sigma; F = 256z+4096.5 pre-scaled index
    auto lutN = [&](float F) -> float {
        F = __builtin_amdgcn_fmed3f(F, 0.0f, FCL_N);
        return lutN_t[(int)F];
    };
    // tanh via hardware exp2+rcp (no 2nd serial gather round)
    auto tanhf_fast = [&](float c) -> float {
        return fmaf(2.f, __builtin_amdgcn_rcpf(1.f + __builtin_exp2f(c * TSC2)), -1.f);
    };

    // ---- register-stationary weights (only MY layer's), per-gate index space
    // tau0 (i), tau1 (f): interp entry space x8 +128
    // tau2 (g): NN x512 +4096.5 (tanh via 2*sigma(2z)-1); tau3 (o): NN x256
    float wi0s[4], b0s[4];
    v8h   wh0[4][2];
    v4f   b1v[4];
    v8h   wi1[4][2], wh1[4][2];
    if (isA) {
        #pragma unroll
        for (int tau = 0; tau < 4; tau++) {
            float sc  = (tau < 2) ? FSC_I : ((tau == 2) ? TG_N : SG_N);
            float off = (tau < 2) ? FOFF_I : IOFF_N;
            int n = tau * 64 + jj;
            wi0s[tau] = Wih0[n] * sc;
            b0s[tau]  = (bih0[n] + bhh0[n]) * sc + off;
            #pragma unroll
            for (int kk = 0; kk < 2; kk++) {
                int k0 = kk * 32 + q * 8;   // B-frag: B[k0..k0+7][n=lane&15]
                v8h a;
                #pragma unroll
                for (int j = 0; j < 8; j++)
                    a[j] = (_Float16)(Whh0[n * HH + k0 + j] * sc);
                wh0[tau][kk] = a;
            }
        }
    } else {
        #pragma unroll
        for (int tau = 0; tau < 4; tau++) {
            float sc  = (tau < 2) ? FSC_I : ((tau == 2) ? TG_N : SG_N);
            float off = (tau < 2) ? FOFF_I : IOFF_N;
            int n = tau * 64 + jj;
            float b1 = (bih1[n] + bhh1[n]) * sc + off;
            b1v[tau] = (v4f){b1, b1, b1, b1};
            #pragma unroll
            for (int kk = 0; kk < 2; kk++) {
                int k0 = kk * 32 + q * 8;
                v8h b, c;
                #pragma unroll
                for (int j = 0; j < 8; j++) {
                    b[j] = (_Float16)(Wih1[n * HH + k0 + j] * sc);
                    c[j] = (_Float16)(Whh1[n * HH + k0 + j] * sc);
                }
                wi1[tau][kk] = b; wh1[tau][kk] = c;
            }
        }
    }

    float cs[4] = {0.f, 0.f, 0.f, 0.f};  // c-state of MY layer, rows mr..mr+3
    __syncthreads();

    // ---- prologue t=0: ha(0) from x(0) only (layer-0 waves) ----
    if (isA) {
        #pragma unroll
        for (int r = 0; r < 4; r++) {
            int m = mr + r;
            float xv = xl[0][m];
            float iv = lutI(fmaf(xv, wi0s[0], b0s[0]));
            float gv = fmaf(2.f, lutN(fmaf(xv, wi0s[2], b0s[2])), -1.f);
            float ov = lutN(fmaf(xv, wi0s[3], b0s[3]));
            cs[r] = iv * gv;
            hs[0][m][jj] = (_Float16)(ov * tanhf_fast(cs[r]));
        }
    }
    __syncthreads();

    // step k: reads buf[p] {ha(k-1), hb(k-2)}, writes buf[pw] {ha(k), hb(k-1)}
    auto step = [&](int k, int p, int pw, bool last) {
        if (isA) {
            // ---- layer 0: 8 MFMAs, x via rank-1 fmaf init ----
            v8h a0 = *(const v8h*)&hs[p][l15][q * 8];          // ha k 0-31
            v8h a1 = *(const v8h*)&hs[p][l15][32 + q * 8];     // ha k 32-63
            int kx = (k < TT) ? k : (TT - 1);                  // k=256: junk
            v4f xv = *(const v4f*)&xl[kx][mr];

            v4f acc[4];
            #pragma unroll
            for (int tau = 0; tau < 4; tau++) {
                #pragma unroll
                for (int r = 0; r < 4; r++)
                    acc[tau][r] = fmaf(xv[r], wi0s[tau], b0s[tau]);
            }
            #pragma unroll
            for (int tau = 0; tau < 4; tau++) {
                acc[tau] = MFMA16(a0, wh0[tau][0], acc[tau]);
                acc[tau] = MFMA16(a1, wh0[tau][1], acc[tau]);
            }
            // NN gathers (g,o: conflicty) first; interp (i,f) math overlaps
            float sv0[4], sv1[4], sv2[4], sv3[4];
            #pragma unroll
            for (int r = 0; r < 4; r++) {
                sv2[r] = lutN(acc[2][r]);
                sv3[r] = lutN(acc[3][r]);
            }
            #pragma unroll
            for (int r = 0; r < 4; r++) {
                sv0[r] = lutI(acc[0][r]);
                sv1[r] = lutI(acc[1][r]);
            }
            _Float16* wp = &hs[pw][mr][jj];
            #pragma unroll
            for (int r = 0; r < 4; r++) {
                float iv = sv0[r], fv = sv1[r];
                float gv = fmaf(2.f, sv2[r], -1.f);
                float ov = sv3[r];
                cs[r] = fmaf(fv, cs[r], iv * gv);
                wp[r * KST] = (_Float16)(ov * tanhf_fast(cs[r]));
            }
        } else {
            // ---- layer 1: 16 MFMAs over [ha | hb], bias as C operand ----
            v8h a0 = *(const v8h*)&hs[p][l15][q * 8];          // ha k 0-31
            v8h a1 = *(const v8h*)&hs[p][l15][32 + q * 8];     // ha k 32-63
            v8h b0 = *(const v8h*)&hs[p][l15][64 + q * 8];     // hb k 0-31
            v8h b1 = *(const v8h*)&hs[p][l15][96 + q * 8];     // hb k 32-63

            v4f acc[4];
            #pragma unroll
            for (int tau = 0; tau < 4; tau++)
                acc[tau] = MFMA16(a0, wi1[tau][0], b1v[tau]);
            #pragma unroll
            for (int tau = 0; tau < 4; tau++) {
                acc[tau] = MFMA16(a1, wi1[tau][1], acc[tau]);
                acc[tau] = MFMA16(b0, wh1[tau][0], acc[tau]);
                acc[tau] = MFMA16(b1, wh1[tau][1], acc[tau]);
            }
            float sv0[4], sv1[4], sv2[4], sv3[4];
            #pragma unroll
            for (int r = 0; r < 4; r++) {
                sv2[r] = lutN(acc[2][r]);
                sv3[r] = lutN(acc[3][r]);
            }
            #pragma unroll
            for (int r = 0; r < 4; r++) {
                sv0[r] = lutI(acc[0][r]);
                sv1[r] = lutI(acc[1][r]);
            }
            _Float16* wp = &hs[pw][mr][64 + jj];
            #pragma unroll
            for (int r = 0; r < 4; r++) {
                float iv = sv0[r], fv = sv1[r];
                float gv = fmaf(2.f, sv2[r], -1.f);
                float ov = sv3[r];
                cs[r] = fmaf(fv, cs[r], iv * gv);
                float hv = ov * tanhf_fast(cs[r]);
                wp[r * KST] = (_Float16)hv;
                if (last) hbF[mr + r][jj] = hv;
            }
        }
        __syncthreads();
    };

    // k = 1..256 (k=256 = layer-1-only epilogue; its ha output junk-but-finite)
    for (int k = 1; k <= TT; k += 2) {
        step(k,     0, 1, false);
        step(k + 1, 1, 0, (k + 1) == TT);
    }

    // ---- out[m][n] = hbF[m][:] . Wlin[n][:] + blin[n] ----
    int m  = tid >> 5;            // 0..15
    int n0 = (tid & 31) * 2;
    float a0o = blin[n0], a1o = blin[n0 + 1];
    #pragma unroll 8
    for (int j = 0; j < HH; j++) {
        float h = hbF[m][j];
        a0o = fmaf(h, Wlin[(n0 + 0) * HH + j], a0o);
        a1o = fmaf(h, Wlin[(n0 + 1) * HH + j], a1o);
    }
    out[(row0 + m) * HH + n0]     = a0o;
    out[(row0 + m) * HH + n0 + 1] = a1o;
}

extern "C" void kernel_launch(void* const* d_in, const int* in_sizes, int n_in,
                              void* d_out, int out_size, void* d_ws, size_t ws_size,
                              hipStream_t stream) {
    const float* x    = (const float*)d_in[0];
    const float* Wih0 = (const float*)d_in[1];
    const float* Whh0 = (const float*)d_in[2];
    const float* bih0 = (const float*)d_in[3];
    const float* bhh0 = (const float*)d_in[4];
    const float* Wih1 = (const float*)d_in[5];
    const float* Whh1 = (const float*)d_in[6];
    const float* bih1 = (const float*)d_in[7];
    const float* bhh1 = (const float*)d_in[8];
    const float* Wlin = (const float*)d_in[9];
    const float* blin = (const float*)d_in[10];
    // 4096 rows / 16 per block = 256 blocks = 1 block/CU, 8 waves (2/SIMD)
    lstm2_kernel<<<256, 512, 0, stream>>>(x, Wih0, Whh0, bih0, bhh0,
                                          Wih1, Whh1, bih1, bhh1,
                                          Wlin, blin, (float*)d_out);
}

// Round 9
// 297.018 us; speedup vs baseline: 1.0663x; 1.0522x over previous
//
#include <hip/hip_runtime.h>

typedef _Float16 v8h __attribute__((ext_vector_type(8)));
typedef float    v4f __attribute__((ext_vector_type(4)));

#define MFMA16(A,B,C) __builtin_amdgcn_mfma_f32_16x16x32_f16((A),(B),(C),0,0,0)

#define RPB 16
#define TT  256
#define HH  64
#define KST 136      // f16 stride per A row: k 0-63 = ha, 64-127 = hb, 8 pad
#define SG  256.0f   // sigmoid LUT index scale (table step 1/256)
#define TG  512.0f   // g-gate tanh index scale (tanh table at z-step 1/512)
#define IOFF 4096.5f // LUT index center + 0.5 NN rounding offset
#define TSC2 -2.88539008f // -2*log2(e): tanh(c)=2*rcp(1+exp2(c*TSC2))-1

// R9: VALU-lean polish of R6 (best: 267us profiled). R6/R7/R8 triplet
// calibrated dur ~ base + a*VALU + k*conflicts with k~0 (gather conflicts
// fully hidden) and a large -> revert R8's interp table (its +2 VALU/value
// cost real, its conflict savings worthless) and cut VALU on the R6 base:
// (1) dedicated tanh LUT for the g-gate (same 512-scale index as the old
// 2*sigma(2z)-1 trick, table holds tanh directly) deletes 4 v_fma/lane-step;
// (2) per-tau MFMA->gather interleave so gather latency hides under the
// other taus' MFMA issue. Keeps R6: 16 real rows, layer-split waves (w<4
// L0: 8 MFMAs, w>=4 L1: 16), no MFMA dup, 1 barrier/step, exp2 tanh(c).
__global__ __launch_bounds__(512, 2)
void lstm2_kernel(const float* __restrict__ x,     // [4096][256]
                  const float* __restrict__ Wih0,  // [256][1]
                  const float* __restrict__ Whh0,  // [256][64]
                  const float* __restrict__ bih0,
                  const float* __restrict__ bhh0,
                  const float* __restrict__ Wih1,  // [256][64]
                  const float* __restrict__ Whh1,  // [256][64]
                  const float* __restrict__ bih1,
                  const float* __restrict__ bhh1,
                  const float* __restrict__ Wlin,  // [64][64]
                  const float* __restrict__ blin,
                  float* __restrict__ out)         // [4096][64]
{
    __shared__ float xl[TT][RPB];                      // 16 KB
    __shared__ __align__(16) _Float16 hs[2][RPB][KST]; // 8.5 KB
    __shared__ float hbF[RPB][HH];                     // 4 KB
    __shared__ float lutS[8192];                       // 32 KB sigma table
    __shared__ float lutT[8192];                       // 32 KB tanh table

    const int tid  = threadIdx.x;
    const int w    = tid >> 6;         // wave 0..7
    const int l15  = tid & 15;         // A-frag row = batch row (no dup)
    const int q    = (tid & 63) >> 4;  // k-group / pointwise row-quad
    const int row0 = (int)blockIdx.x * RPB;
    const int jj   = (w & 3) * 16 + l15;  // gate column 0..63
    const bool isA = (w < 4);          // wave-uniform: layer0 vs layer1
    const int  mr  = q * 4;            // my pointwise row base (0,4,8,12)

    for (int idx = tid; idx < RPB * TT; idx += 512) {
        int m = idx & 15, t = idx >> 4;
        xl[t][m] = x[(row0 + m) * TT + t];
    }
    for (int idx = tid; idx < 2 * RPB * KST; idx += 512)
        ((_Float16*)hs)[idx] = (_Float16)0.f;
    for (int i = tid; i < 8192; i += 512) {
        float e = __expf(-(i - 4096) * (1.0f / 256.0f));
        lutS[i] = 1.0f / (1.0f + e);          // sigma((i-4096)/256)
        lutT[i] = 2.0f / (1.0f + e) - 1.0f;   // tanh((i-4096)/512)
    }

    // NN lookups; F is a pre-scaled index (sigma: 256z+4096.5, tanh: 512z+4096.5)
    auto lutSv = [&](float F) -> float {
        F = __builtin_amdgcn_fmed3f(F, 0.0f, 8191.0f);
        return lutS[(int)F];
    };
    auto lutTv = [&](float F) -> float {
        F = __builtin_amdgcn_fmed3f(F, 0.0f, 8191.0f);
        return lutT[(int)F];
    };
    // tanh(c) via hardware exp2+rcp (no gather on the c-path)
    auto tanhf_fast = [&](float c) -> float {
        return fmaf(2.f, __builtin_amdgcn_rcpf(1.f + __builtin_exp2f(c * TSC2)), -1.f);
    };

    // ---- register-stationary weights (only MY layer's), LUT index space ----
    float wi0s[4], b0s[4];
    v8h   wh0[4][2];
    v4f   b1v[4];
    v8h   wi1[4][2], wh1[4][2];
    if (isA) {
        #pragma unroll
        for (int tau = 0; tau < 4; tau++) {
            float sc = (tau == 2) ? TG : SG;
            int n = tau * 64 + jj;
            wi0s[tau] = Wih0[n] * sc;
            b0s[tau]  = (bih0[n] + bhh0[n]) * sc + IOFF;
            #pragma unroll
            for (int kk = 0; kk < 2; kk++) {
                int k0 = kk * 32 + q * 8;   // B-frag: B[k0..k0+7][n=lane&15]
                v8h a;
                #pragma unroll
                for (int j = 0; j < 8; j++)
                    a[j] = (_Float16)(Whh0[n * HH + k0 + j] * sc);
                wh0[tau][kk] = a;
            }
        }
    } else {
        #pragma unroll
        for (int tau = 0; tau < 4; tau++) {
            float sc = (tau == 2) ? TG : SG;
            int n = tau * 64 + jj;
            float b1 = (bih1[n] + bhh1[n]) * sc + IOFF;
            b1v[tau] = (v4f){b1, b1, b1, b1};
            #pragma unroll
            for (int kk = 0; kk < 2; kk++) {
                int k0 = kk * 32 + q * 8;
                v8h b, c;
                #pragma unroll
                for (int j = 0; j < 8; j++) {
                    b[j] = (_Float16)(Wih1[n * HH + k0 + j] * sc);
                    c[j] = (_Float16)(Whh1[n * HH + k0 + j] * sc);
                }
                wi1[tau][kk] = b; wh1[tau][kk] = c;
            }
        }
    }

    float cs[4] = {0.f, 0.f, 0.f, 0.f};  // c-state of MY layer, rows mr..mr+3
    __syncthreads();

    // ---- prologue t=0: ha(0) from x(0) only (layer-0 waves) ----
    if (isA) {
        #pragma unroll
        for (int r = 0; r < 4; r++) {
            int m = mr + r;
            float xv = xl[0][m];
            float iv = lutSv(fmaf(xv, wi0s[0], b0s[0]));
            float gv = lutTv(fmaf(xv, wi0s[2], b0s[2]));
            float ov = lutSv(fmaf(xv, wi0s[3], b0s[3]));
            cs[r] = iv * gv;
            hs[0][m][jj] = (_Float16)(ov * tanhf_fast(cs[r]));
        }
    }
    __syncthreads();

    // step k: reads buf[p] {ha(k-1), hb(k-2)}, writes buf[pw] {ha(k), hb(k-1)}
    auto step = [&](int k, int p, int pw, bool last) {
        float sv[4][4];   // [tau][r]
        if (isA) {
            // ---- layer 0: 8 MFMAs, x via rank-1 fmaf init ----
            v8h a0 = *(const v8h*)&hs[p][l15][q * 8];          // ha k 0-31
            v8h a1 = *(const v8h*)&hs[p][l15][32 + q * 8];     // ha k 32-63
            int kx = (k < TT) ? k : (TT - 1);                  // k=256: junk
            v4f xv = *(const v4f*)&xl[kx][mr];

            // per-tau: MFMA chain then its gathers -> gather latency hides
            // under the next tau's MFMA issue
            #pragma unroll
            for (int tau = 0; tau < 4; tau++) {
                v4f acc;
                #pragma unroll
                for (int r = 0; r < 4; r++)
                    acc[r] = fmaf(xv[r], wi0s[tau], b0s[tau]);
                acc = MFMA16(a0, wh0[tau][0], acc);
                acc = MFMA16(a1, wh0[tau][1], acc);
                if (tau == 2) {
                    #pragma unroll
                    for (int r = 0; r < 4; r++) sv[tau][r] = lutTv(acc[r]);
                } else {
                    #pragma unroll
                    for (int r = 0; r < 4; r++) sv[tau][r] = lutSv(acc[r]);
                }
            }
            _Float16* wp = &hs[pw][mr][jj];
            #pragma unroll
            for (int r = 0; r < 4; r++) {
                float iv = sv[0][r], fv = sv[1][r];
                float gv = sv[2][r], ov = sv[3][r];
                cs[r] = fmaf(fv, cs[r], iv * gv);
                wp[r * KST] = (_Float16)(ov * tanhf_fast(cs[r]));
            }
        } else {
            // ---- layer 1: 16 MFMAs over [ha | hb], bias as C operand ----
            v8h a0 = *(const v8h*)&hs[p][l15][q * 8];          // ha k 0-31
            v8h a1 = *(const v8h*)&hs[p][l15][32 + q * 8];     // ha k 32-63
            v8h b0 = *(const v8h*)&hs[p][l15][64 + q * 8];     // hb k 0-31
            v8h b1 = *(const v8h*)&hs[p][l15][96 + q * 8];     // hb k 32-63

            #pragma unroll
            for (int tau = 0; tau < 4; tau++) {
                v4f acc = MFMA16(a0, wi1[tau][0], b1v[tau]);
                acc = MFMA16(a1, wi1[tau][1], acc);
                acc = MFMA16(b0, wh1[tau][0], acc);
                acc = MFMA16(b1, wh1[tau][1], acc);
                if (tau == 2) {
                    #pragma unroll
                    for (int r = 0; r < 4; r++) sv[tau][r] = lutTv(acc[r]);
                } else {
                    #pragma unroll
                    for (int r = 0; r < 4; r++) sv[tau][r] = lutSv(acc[r]);
                }
            }
            _Float16* wp = &hs[pw][mr][64 + jj];
            #pragma unroll
            for (int r = 0; r < 4; r++) {
                float iv = sv[0][r], fv = sv[1][r];
                float gv = sv[2][r], ov = sv[3][r];
                cs[r] = fmaf(fv, cs[r], iv * gv);
                float hv = ov * tanhf_fast(cs[r]);
                wp[r * KST] = (_Float16)hv;
                if (last) hbF[mr + r][jj] = hv;
            }
        }
        __syncthreads();
    };

    // k = 1..256 (k=256 = layer-1-only epilogue; its ha output junk-but-finite)
    for (int k = 1; k <= TT; k += 2) {
        step(k,     0, 1, false);
        step(k + 1, 1, 0, (k + 1) == TT);
    }

    // ---- out[m][n] = hbF[m][:] . Wlin[n][:] + blin[n] ----
    int m  = tid >> 5;            // 0..15
    int n0 = (tid & 31) * 2;
    float a0o = blin[n0], a1o = blin[n0 + 1];
    #pragma unroll 8
    for (int j = 0; j < HH; j++) {
        float h = hbF[m][j];
        a0o = fmaf(h, Wlin[(n0 + 0) * HH + j], a0o);
        a1o = fmaf(h, Wlin[(n0 + 1) * HH + j], a1o);
    }
    out[(row0 + m) * HH + n0]     = a0o;
    out[(row0 + m) * HH + n0 + 1] = a1o;
}

extern "C" void kernel_launch(void* const* d_in, const int* in_sizes, int n_in,
                              void* d_out, int out_size, void* d_ws, size_t ws_size,
                              hipStream_t stream) {
    const float* x    = (const float*)d_in[0];
    const float* Wih0 = (const float*)d_in[1];
    const float* Whh0 = (const float*)d_in[2];
    const float* bih0 = (const float*)d_in[3];
    const float* bhh0 = (const float*)d_in[4];
    const float* Wih1 = (const float*)d_in[5];
    const float* Whh1 = (const float*)d_in[6];
    const float* bih1 = (const float*)d_in[7];
    const float* bhh1 = (const float*)d_in[8];
    const float* Wlin = (const float*)d_in[9];
    const float* blin = (const float*)d_in[10];
    // 4096 rows / 16 per block = 256 blocks = 1 block/CU, 8 waves (2/SIMD)
    lstm2_kernel<<<256, 512, 0, stream>>>(x, Wih0, Whh0, bih0, bhh0,
                                          Wih1, Whh1, bih1, bhh1,
                                          Wlin, blin, (float*)d_out);
}

// Round 11
// 270.585 us; speedup vs baseline: 1.1705x; 1.0977x over previous
//
#include <hip/hip_runtime.h>

typedef _Float16 v8h __attribute__((ext_vector_type(8)));
typedef float    v4f __attribute__((ext_vector_type(4)));

#define MFMA16(A,B,C) __builtin_amdgcn_mfma_f32_16x16x32_f16((A),(B),(C),0,0,0)

#define RPB 16
#define TT  256
#define HH  64
#define KST 136      // f16 stride per A row: k 0-63 = ha, 64-127 = hb, 8 pad
#define SG  256.0f   // sigmoid LUT index scale (table step 1/256)
#define TG  512.0f   // g-gate tanh index scale (tanh table at z-step 1/512)
#define IOFF 4096.5f // LUT index center + 0.5 NN rounding offset
#define TSC2 -2.88539008f // -2*log2(e): tanh(c)=2*rcp(1+exp2(c*TSC2))-1

// R11 = R10 resubmission (Trio-nursery infra flake; kernel diff vs known-
// good R9 is only wave-uniform s_setprio hints — no correctness surface).
// R10 theory: step is ~50% latency-stall with 2 role-split waves/SIMD;
// setprio(1) around each tau's MFMA cluster (T5) is the measured lever for
// role-split schedules (attn +4-7% m191; null on lockstep m190). Elevate
// the wave during its MFMA burst so the matrix pipe stays fed while the
// SIMD-mate is mid-gather/pointwise. All else identical to R9 (best, 255us
// profiled): 16 real rows, layer-split waves (w<4 L0: 8 MFMAs, w>=4 L1:
// 16), dual NN LUTs (sigma + direct tanh), per-tau MFMA->gather
// interleave, 1 barrier/step, exp2 tanh(c).
__global__ __launch_bounds__(512, 2)
void lstm2_kernel(const float* __restrict__ x,     // [4096][256]
                  const float* __restrict__ Wih0,  // [256][1]
                  const float* __restrict__ Whh0,  // [256][64]
                  const float* __restrict__ bih0,
                  const float* __restrict__ bhh0,
                  const float* __restrict__ Wih1,  // [256][64]
                  const float* __restrict__ Whh1,  // [256][64]
                  const float* __restrict__ bih1,
                  const float* __restrict__ bhh1,
                  const float* __restrict__ Wlin,  // [64][64]
                  const float* __restrict__ blin,
                  float* __restrict__ out)         // [4096][64]
{
    __shared__ float xl[TT][RPB];                      // 16 KB
    __shared__ __align__(16) _Float16 hs[2][RPB][KST]; // 8.5 KB
    __shared__ float hbF[RPB][HH];                     // 4 KB
    __shared__ float lutS[8192];                       // 32 KB sigma table
    __shared__ float lutT[8192];                       // 32 KB tanh table

    const int tid  = threadIdx.x;
    const int w    = tid >> 6;         // wave 0..7
    const int l15  = tid & 15;         // A-frag row = batch row (no dup)
    const int q    = (tid & 63) >> 4;  // k-group / pointwise row-quad
    const int row0 = (int)blockIdx.x * RPB;
    const int jj   = (w & 3) * 16 + l15;  // gate column 0..63
    const bool isA = (w < 4);          // wave-uniform: layer0 vs layer1
    const int  mr  = q * 4;            // my pointwise row base (0,4,8,12)

    for (int idx = tid; idx < RPB * TT; idx += 512) {
        int m = idx & 15, t = idx >> 4;
        xl[t][m] = x[(row0 + m) * TT + t];
    }
    for (int idx = tid; idx < 2 * RPB * KST; idx += 512)
        ((_Float16*)hs)[idx] = (_Float16)0.f;
    for (int i = tid; i < 8192; i += 512) {
        float e = __expf(-(i - 4096) * (1.0f / 256.0f));
        lutS[i] = 1.0f / (1.0f + e);          // sigma((i-4096)/256)
        lutT[i] = 2.0f / (1.0f + e) - 1.0f;   // tanh((i-4096)/512)
    }

    // NN lookups; F is a pre-scaled index (sigma: 256z+4096.5, tanh: 512z+4096.5)
    auto lutSv = [&](float F) -> float {
        F = __builtin_amdgcn_fmed3f(F, 0.0f, 8191.0f);
        return lutS[(int)F];
    };
    auto lutTv = [&](float F) -> float {
        F = __builtin_amdgcn_fmed3f(F, 0.0f, 8191.0f);
        return lutT[(int)F];
    };
    // tanh(c) via hardware exp2+rcp (no gather on the c-path)
    auto tanhf_fast = [&](float c) -> float {
        return fmaf(2.f, __builtin_amdgcn_rcpf(1.f + __builtin_exp2f(c * TSC2)), -1.f);
    };

    // ---- register-stationary weights (only MY layer's), LUT index space ----
    float wi0s[4], b0s[4];
    v8h   wh0[4][2];
    v4f   b1v[4];
    v8h   wi1[4][2], wh1[4][2];
    if (isA) {
        #pragma unroll
        for (int tau = 0; tau < 4; tau++) {
            float sc = (tau == 2) ? TG : SG;
            int n = tau * 64 + jj;
            wi0s[tau] = Wih0[n] * sc;
            b0s[tau]  = (bih0[n] + bhh0[n]) * sc + IOFF;
            #pragma unroll
            for (int kk = 0; kk < 2; kk++) {
                int k0 = kk * 32 + q * 8;   // B-frag: B[k0..k0+7][n=lane&15]
                v8h a;
                #pragma unroll
                for (int j = 0; j < 8; j++)
                    a[j] = (_Float16)(Whh0[n * HH + k0 + j] * sc);
                wh0[tau][kk] = a;
            }
        }
    } else {
        #pragma unroll
        for (int tau = 0; tau < 4; tau++) {
            float sc = (tau == 2) ? TG : SG;
            int n = tau * 64 + jj;
            float b1 = (bih1[n] + bhh1[n]) * sc + IOFF;
            b1v[tau] = (v4f){b1, b1, b1, b1};
            #pragma unroll
            for (int kk = 0; kk < 2; kk++) {
                int k0 = kk * 32 + q * 8;
                v8h b, c;
                #pragma unroll
                for (int j = 0; j < 8; j++) {
                    b[j] = (_Float16)(Wih1[n * HH + k0 + j] * sc);
                    c[j] = (_Float16)(Whh1[n * HH + k0 + j] * sc);
                }
                wi1[tau][kk] = b; wh1[tau][kk] = c;
            }
        }
    }

    float cs[4] = {0.f, 0.f, 0.f, 0.f};  // c-state of MY layer, rows mr..mr+3
    __syncthreads();

    // ---- prologue t=0: ha(0) from x(0) only (layer-0 waves) ----
    if (isA) {
        #pragma unroll
        for (int r = 0; r < 4; r++) {
            int m = mr + r;
            float xv = xl[0][m];
            float iv = lutSv(fmaf(xv, wi0s[0], b0s[0]));
            float gv = lutTv(fmaf(xv, wi0s[2], b0s[2]));
            float ov = lutSv(fmaf(xv, wi0s[3], b0s[3]));
            cs[r] = iv * gv;
            hs[0][m][jj] = (_Float16)(ov * tanhf_fast(cs[r]));
        }
    }
    __syncthreads();

    // step k: reads buf[p] {ha(k-1), hb(k-2)}, writes buf[pw] {ha(k), hb(k-1)}
    auto step = [&](int k, int p, int pw, bool last) {
        float sv[4][4];   // [tau][r]
        if (isA) {
            // ---- layer 0: 8 MFMAs, x via rank-1 fmaf init ----
            v8h a0 = *(const v8h*)&hs[p][l15][q * 8];          // ha k 0-31
            v8h a1 = *(const v8h*)&hs[p][l15][32 + q * 8];     // ha k 32-63
            int kx = (k < TT) ? k : (TT - 1);                  // k=256: junk
            v4f xv = *(const v4f*)&xl[kx][mr];

            // per-tau: MFMA chain (prio-boosted) then its gathers -> gather
            // latency hides under the next tau's MFMA issue
            #pragma unroll
            for (int tau = 0; tau < 4; tau++) {
                v4f acc;
                #pragma unroll
                for (int r = 0; r < 4; r++)
                    acc[r] = fmaf(xv[r], wi0s[tau], b0s[tau]);
                __builtin_amdgcn_s_setprio(1);
                acc = MFMA16(a0, wh0[tau][0], acc);
                acc = MFMA16(a1, wh0[tau][1], acc);
                __builtin_amdgcn_s_setprio(0);
                if (tau == 2) {
                    #pragma unroll
                    for (int r = 0; r < 4; r++) sv[tau][r] = lutTv(acc[r]);
                } else {
                    #pragma unroll
                    for (int r = 0; r < 4; r++) sv[tau][r] = lutSv(acc[r]);
                }
            }
            _Float16* wp = &hs[pw][mr][jj];
            #pragma unroll
            for (int r = 0; r < 4; r++) {
                float iv = sv[0][r], fv = sv[1][r];
                float gv = sv[2][r], ov = sv[3][r];
                cs[r] = fmaf(fv, cs[r], iv * gv);
                wp[r * KST] = (_Float16)(ov * tanhf_fast(cs[r]));
            }
        } else {
            // ---- layer 1: 16 MFMAs over [ha | hb], bias as C operand ----
            v8h a0 = *(const v8h*)&hs[p][l15][q * 8];          // ha k 0-31
            v8h a1 = *(const v8h*)&hs[p][l15][32 + q * 8];     // ha k 32-63
            v8h b0 = *(const v8h*)&hs[p][l15][64 + q * 8];     // hb k 0-31
            v8h b1 = *(const v8h*)&hs[p][l15][96 + q * 8];     // hb k 32-63

            #pragma unroll
            for (int tau = 0; tau < 4; tau++) {
                __builtin_amdgcn_s_setprio(1);
                v4f acc = MFMA16(a0, wi1[tau][0], b1v[tau]);
                acc = MFMA16(a1, wi1[tau][1], acc);
                acc = MFMA16(b0, wh1[tau][0], acc);
                acc = MFMA16(b1, wh1[tau][1], acc);
                __builtin_amdgcn_s_setprio(0);
                if (tau == 2) {
                    #pragma unroll
                    for (int r = 0; r < 4; r++) sv[tau][r] = lutTv(acc[r]);
                } else {
                    #pragma unroll
                    for (int r = 0; r < 4; r++) sv[tau][r] = lutSv(acc[r]);
                }
            }
            _Float16* wp = &hs[pw][mr][64 + jj];
            #pragma unroll
            for (int r = 0; r < 4; r++) {
                float iv = sv[0][r], fv = sv[1][r];
                float gv = sv[2][r], ov = sv[3][r];
                cs[r] = fmaf(fv, cs[r], iv * gv);
                float hv = ov * tanhf_fast(cs[r]);
                wp[r * KST] = (_Float16)hv;
                if (last) hbF[mr + r][jj] = hv;
            }
        }
        __syncthreads();
    };

    // k = 1..256 (k=256 = layer-1-only epilogue; its ha output junk-but-finite)
    for (int k = 1; k <= TT; k += 2) {
        step(k,     0, 1, false);
        step(k + 1, 1, 0, (k + 1) == TT);
    }

    // ---- out[m][n] = hbF[m][:] . Wlin[n][:] + blin[n] ----
    int m  = tid >> 5;            // 0..15
    int n0 = (tid & 31) * 2;
    float a0o = blin[n0], a1o = blin[n0 + 1];
    #pragma unroll 8
    for (int j = 0; j < HH; j++) {
        float h = hbF[m][j];
        a0o = fmaf(h, Wlin[(n0 + 0) * HH + j], a0o);
        a1o = fmaf(h, Wlin[(n0 + 1) * HH + j], a1o);
    }
    out[(row0 + m) * HH + n0]     = a0o;
    out[(row0 + m) * HH + n0 + 1] = a1o;
}

extern "C" void kernel_launch(void* const* d_in, const int* in_sizes, int n_in,
                              void* d_out, int out_size, void* d_ws, size_t ws_size,
                              hipStream_t stream) {
    const float* x    = (const float*)d_in[0];
    const float* Wih0 = (const float*)d_in[1];
    const float* Whh0 = (const float*)d_in[2];
    const float* bih0 = (const float*)d_in[3];
    const float* bhh0 = (const float*)d_in[4];
    const float* Wih1 = (const float*)d_in[5];
    const float* Whh1 = (const float*)d_in[6];
    const float* bih1 = (const float*)d_in[7];
    const float* bhh1 = (const float*)d_in[8];
    const float* Wlin = (const float*)d_in[9];
    const float* blin = (const float*)d_in[10];
    // 4096 rows / 16 per block = 256 blocks = 1 block/CU, 8 waves (2/SIMD)
    lstm2_kernel<<<256, 512, 0, stream>>>(x, Wih0, Whh0, bih0, bhh0,
                                          Wih1, Whh1, bih1, bhh1,
                                          Wlin, blin, (float*)d_out);
}